// Round 4
// baseline (762.970 us; speedup 1.0000x reference)
//
#include <hip/hip_runtime.h>
#include <stdint.h>

#define HID 128

typedef __attribute__((ext_vector_type(8))) short bf16x8;
typedef __attribute__((ext_vector_type(4))) float f32x4;

__device__ __forceinline__ float bf2f(unsigned short u){
  union { unsigned int i; float f; } x; x.i = ((unsigned int)u) << 16; return x.f;
}
__device__ __forceinline__ unsigned short f2bf(float f){
  union { float f; unsigned int i; } x; x.f = f;
  unsigned int b = x.i;
  return (unsigned short)((b + 0x7fffu + ((b >> 16) & 1u)) >> 16);
}

// ---------------- dtype detection: fp32 storage (flag=1) vs bf16 (flag=0) ----------------
__global__ void detect_dtype(const unsigned short* __restrict__ x, int* __restrict__ flag){
  if (threadIdx.x == 0 && blockIdx.x == 0){
    int czero = 0, cbig = 0;
    for (int i = 0; i < 256; ++i){
      unsigned short u = x[i];
      int ex = (u >> 7) & 0xFF;
      if ((i & 1) == 0 && u == 0) czero++;
      if (ex >= 140) cbig++;
    }
    flag[0] = (czero >= 32 || cbig >= 8) ? 1 : 0;
  }
}

// ---------------- canonicalization ----------------
struct CvList {
  const void* src[16];
  float* dst[16];
  int cnt[16];
  int n;
};
__global__ __launch_bounds__(256) void conv_weights(CvList L, const int* __restrict__ flag){
  bool isf32 = flag[0] != 0;
  for (int a = 0; a < L.n; ++a){
    const void* s = L.src[a];
    float* d = L.dst[a];
    int c = L.cnt[a];
    for (int i = blockIdx.x*256 + threadIdx.x; i < c; i += gridDim.x*256){
      d[i] = isf32 ? ((const float*)s)[i] : bf2f(((const unsigned short*)s)[i]);
    }
  }
}
__global__ __launch_bounds__(256) void conv_bf16(const void* __restrict__ src,
                                                 unsigned short* __restrict__ dst,
                                                 int n4, const int* __restrict__ flag){
  int i = blockIdx.x*256 + threadIdx.x;
  if (i >= n4) return;
  if (flag[0]){
    float4 v = ((const float4*)src)[i];
    ushort4 o; o.x = f2bf(v.x); o.y = f2bf(v.y); o.z = f2bf(v.z); o.w = f2bf(v.w);
    ((ushort4*)dst)[i] = o;
  } else {
    ((ushort4*)dst)[i] = ((const ushort4*)src)[i];
  }
}

// ---------------- precompute M = W_bond @ (W_edge @ att_edge), cbias = b_bond @ ve ----
__global__ __launch_bounds__(256) void precompute_M(
    const float* __restrict__ We, const float* __restrict__ ae,
    const float* __restrict__ Wb, const float* __restrict__ bb,
    float* __restrict__ Mout, float* __restrict__ cb)
{
  __shared__ float ve[128*12];
  int tid = threadIdx.x;
  for (int i = tid; i < 128*12; i += 256){
    int c = i / 12, lh = i % 12; int l = lh >> 2, h = lh & 3;
    float s = 0.f;
    for (int d = 0; d < 32; ++d)
      s += We[l*16384 + c*128 + h*32 + d] * ae[l*128 + h*32 + d];
    ve[i] = s;
  }
  __syncthreads();
  for (int i = tid; i < 16*12; i += 256){
    int k = i / 12, lh = i % 12;
    float s = 0.f;
    for (int c = 0; c < 128; ++c) s += Wb[k*128 + c] * ve[c*12 + lh];
    Mout[i] = s;
  }
  for (int i = tid; i < 12; i += 256){
    float s = 0.f;
    for (int c = 0; c < 128; ++c) s += bb[c] * ve[c*12 + i];
    cb[i] = s;
  }
}

// ---------------- CSR build ----------------
__global__ __launch_bounds__(256) void deg_count(const int* __restrict__ ei, int E, int* __restrict__ deg){
  int e = blockIdx.x*256 + threadIdx.x;
  if (e < E) atomicAdd(&deg[ei[E + e]], 1);
}
__global__ __launch_bounds__(256) void scan_part(const int* __restrict__ deg, int* __restrict__ part, int N){
  int base = blockIdx.x*1024;
  int s = 0;
  for (int i = threadIdx.x; i < 1024; i += 256){ int j = base + i; if (j < N) s += deg[j]; }
  __shared__ int sh[256];
  sh[threadIdx.x] = s; __syncthreads();
  for (int m = 128; m > 0; m >>= 1){ if (threadIdx.x < m) sh[threadIdx.x] += sh[threadIdx.x + m]; __syncthreads(); }
  if (threadIdx.x == 0) part[blockIdx.x] = sh[0];
}
__global__ void scan_top(int* part, int P){
  if (threadIdx.x == 0 && blockIdx.x == 0){
    int acc = 0;
    for (int i = 0; i < P; ++i){ int v = part[i]; part[i] = acc; acc += v; }
  }
}
__global__ __launch_bounds__(256) void scan_write(const int* __restrict__ deg, const int* __restrict__ part,
                                                  int* __restrict__ row, int N, int E){
  int base = blockIdx.x*1024 + threadIdx.x*4;
  int v0=0,v1=0,v2=0,v3=0;
  if (base+0 < N) v0 = deg[base+0];
  if (base+1 < N) v1 = deg[base+1];
  if (base+2 < N) v2 = deg[base+2];
  if (base+3 < N) v3 = deg[base+3];
  int s = v0+v1+v2+v3;
  __shared__ int sh[256];
  sh[threadIdx.x] = s; __syncthreads();
  for (int m = 1; m < 256; m <<= 1){
    int t = (threadIdx.x >= m) ? sh[threadIdx.x - m] : 0;
    __syncthreads();
    sh[threadIdx.x] += t;
    __syncthreads();
  }
  int excl = sh[threadIdx.x] - s + part[blockIdx.x];
  if (base+0 < N) row[base+0] = excl; excl += v0;
  if (base+1 < N) row[base+1] = excl; excl += v1;
  if (base+2 < N) row[base+2] = excl; excl += v2;
  if (base+3 < N) row[base+3] = excl;
  if (blockIdx.x == 0 && threadIdx.x == 0) row[N] = E;
}
__global__ __launch_bounds__(256) void csr_fill(const int* __restrict__ ei, int E, const int* __restrict__ row,
                                                int* __restrict__ cursor, int* __restrict__ csr_src,
                                                int* __restrict__ csr_eid){
  int e = blockIdx.x*256 + threadIdx.x;
  if (e >= E) return;
  int s = ei[e], d = ei[E + e];
  int pos = atomicAdd(&cursor[d], 1);
  int idx = row[d] + pos;
  csr_src[idx] = s;
  csr_eid[idx] = e;
}
// gather edge_attr into CSR order (bf16), once — layer-invariant
__global__ __launch_bounds__(256) void gather_eattr(const void* __restrict__ eattr,
                                                    const int* __restrict__ csr_eid,
                                                    unsigned short* __restrict__ ecsr,
                                                    int E, const int* __restrict__ flag){
  int pos = blockIdx.x*256 + threadIdx.x;
  if (pos >= E) return;
  int eid = csr_eid[pos];
  uint4 o0, o1;
  if (flag[0]){
    const float4* pp = (const float4*)((const float*)eattr + (size_t)eid*16);
    float4 a = pp[0], b = pp[1], c = pp[2], d = pp[3];
    o0.x = f2bf(a.x) | ((unsigned)f2bf(a.y) << 16);
    o0.y = f2bf(a.z) | ((unsigned)f2bf(a.w) << 16);
    o0.z = f2bf(b.x) | ((unsigned)f2bf(b.y) << 16);
    o0.w = f2bf(b.z) | ((unsigned)f2bf(b.w) << 16);
    o1.x = f2bf(c.x) | ((unsigned)f2bf(c.y) << 16);
    o1.y = f2bf(c.z) | ((unsigned)f2bf(c.w) << 16);
    o1.z = f2bf(d.x) | ((unsigned)f2bf(d.y) << 16);
    o1.w = f2bf(d.z) | ((unsigned)f2bf(d.w) << 16);
  } else {
    const uint4* pp = (const uint4*)((const unsigned short*)eattr + (size_t)eid*16);
    o0 = pp[0]; o1 = pp[1];
  }
  uint4* op = (uint4*)(ecsr + (size_t)pos*16);
  op[0] = o0; op[1] = o1;
}

// ---------------- MFMA GEMM: out[N,128] = A[N,K](bf16) @ W[K,128] (+bias) ----------------
// OUTMODE: 0 = bf16 out, 1 = external out (flag: 1=fp32, 0=bf16), 2 = dual fp32 Out + bf16 Out2
template<int K, int OUTMODE>
__global__ __launch_bounds__(256) void mfma_lin(const unsigned short* __restrict__ A,
                                                const float* __restrict__ W,
                                                const float* __restrict__ bias,
                                                void* __restrict__ Out, void* __restrict__ Out2,
                                                int N, const int* __restrict__ flag)
{
  constexpr int KP = K + 8;
  __shared__ unsigned short WT[128*KP];
  int tid = threadIdx.x;
  for (int i = tid; i < K*128; i += 256){
    int k = i >> 7, ch = i & 127;
    WT[ch*KP + k] = f2bf(W[i]);
  }
  __syncthreads();
  int wid = tid >> 6, lane = tid & 63;
  int quad = lane >> 4, m = lane & 15;
  int nodeBase = blockIdx.x*64 + wid*16;
  int node = nodeBase + m;
  int nodeC = (node < N) ? node : 0;
  bf16x8 afr[K/32];
  #pragma unroll
  for (int kb = 0; kb < K/32; ++kb)
    afr[kb] = *(const bf16x8*)(A + (size_t)nodeC*K + kb*32 + quad*8);
  f32x4 acc[8] = {};
  #pragma unroll
  for (int t = 0; t < 8; ++t){
    #pragma unroll
    for (int kb = 0; kb < K/32; ++kb){
      bf16x8 bfr = *(const bf16x8*)&WT[(t*16 + m)*KP + kb*32 + quad*8];
      acc[t] = __builtin_amdgcn_mfma_f32_16x16x32_bf16(afr[kb], bfr, acc[t], 0, 0, 0);
    }
  }
  bool f32out = (OUTMODE == 1) && (flag[0] != 0);
  #pragma unroll
  for (int t = 0; t < 8; ++t){
    int ch = t*16 + m;
    float bv = bias ? bias[ch] : 0.f;
    #pragma unroll
    for (int r2 = 0; r2 < 4; ++r2){
      int nd = nodeBase + quad*4 + r2;
      if (nd < N){
        float v = acc[t][r2] + bv;
        if (OUTMODE == 0){
          ((unsigned short*)Out)[(size_t)nd*HID + ch] = f2bf(v);
        } else if (OUTMODE == 2){
          ((float*)Out)[(size_t)nd*HID + ch] = v;
          ((unsigned short*)Out2)[(size_t)nd*HID + ch] = f2bf(v);
        } else {
          if (f32out) ((float*)Out)[(size_t)nd*HID + ch] = v;
          else        ((unsigned short*)Out)[(size_t)nd*HID + ch] = f2bf(v);
        }
      }
    }
  }
}

// ---------------- attention scores: thread per (node, head) ----------------
__global__ __launch_bounds__(256) void att_scores(const unsigned short* __restrict__ xh,
                                                  const float* __restrict__ asv,
                                                  const float* __restrict__ adv,
                                                  float* __restrict__ a_src, float* __restrict__ a_dst,
                                                  int N)
{
  __shared__ float sAs[128], sAd[128];
  int tid = threadIdx.x;
  if (tid < 128){ sAs[tid] = asv[tid]; sAd[tid] = adv[tid]; }
  __syncthreads();
  int idx = blockIdx.x*256 + tid;
  if (idx >= N*4) return;
  int n = idx >> 2, h = idx & 3;
  const uint4* p = (const uint4*)(xh + (size_t)n*128 + h*32);
  float vs = 0.f, vd = 0.f;
  #pragma unroll
  for (int q = 0; q < 4; ++q){
    uint4 u = p[q];
    unsigned w[4] = {u.x, u.y, u.z, u.w};
    #pragma unroll
    for (int k = 0; k < 4; ++k){
      float v0 = bf2f((unsigned short)(w[k] & 0xffffu));
      float v1 = bf2f((unsigned short)(w[k] >> 16));
      int c = h*32 + q*8 + k*2;
      vs += v0*sAs[c] + v1*sAs[c+1];
      vd += v0*sAd[c] + v1*sAd[c+1];
    }
  }
  a_src[idx] = vs;
  a_dst[idx] = vd;
}

__device__ __forceinline__ float lrelu(float x){ return x > 0.f ? x : 0.2f*x; }
__device__ __forceinline__ float expg(float x){ return __expf(fminf(x, 0.f)); }

// compute per-edge alpha + ae from CSR-ordered eattr (one edge per call)
__device__ __forceinline__ void edge_alpha_at(const unsigned short* __restrict__ ecsr, int pos,
                                              const float (*sM)[4], const float* sC,
                                              const int* __restrict__ csr_src,
                                              const float* __restrict__ a_src, float4 ad,
                                              float* al, float* ae, int* srcOut)
{
  int src = csr_src[pos];
  const uint4* ep = (const uint4*)(ecsr + (size_t)pos*16);
  uint4 u0 = ep[0], u1 = ep[1];
  unsigned w[8] = {u0.x,u0.y,u0.z,u0.w,u1.x,u1.y,u1.z,u1.w};
  float a0 = sC[0], a1 = sC[1], a2 = sC[2], a3 = sC[3];
  #pragma unroll
  for (int k = 0; k < 16; ++k){
    float v = bf2f((unsigned short)((k & 1) ? (w[k>>1] >> 16) : (w[k>>1] & 0xffffu)));
    a0 += v*sM[k][0]; a1 += v*sM[k][1]; a2 += v*sM[k][2]; a3 += v*sM[k][3];
  }
  ae[0] = a0; ae[1] = a1; ae[2] = a2; ae[3] = a3;
  float4 as4 = *(const float4*)(a_src + (size_t)src*4);
  al[0] = lrelu(as4.x + ad.x + a0);
  al[1] = lrelu(as4.y + ad.y + a1);
  al[2] = lrelu(as4.z + ad.z + a2);
  al[3] = lrelu(as4.w + ad.w + a3);
  *srcOut = src;
}

// ---------------- GAT aggregation v3: wave per node, alpha fused, bf16 xh gather ----
__global__ __launch_bounds__(256) void gat_agg(
    const unsigned short* __restrict__ xh, const unsigned short* __restrict__ ecsr,
    const int* __restrict__ csr_src, const int* __restrict__ row,
    const float* __restrict__ a_src, const float* __restrict__ a_dst,
    const float* __restrict__ Mmat, const float* __restrict__ cbias,
    const float* __restrict__ bconv, float* __restrict__ hout, int N, int layer)
{
  __shared__ float sM[16][4];
  __shared__ float sC[4];
  __shared__ float sP[4][4][64];   // [wave][head][edge]
  __shared__ int   sOff[4][64];    // [wave][edge] src byte offsets
  int tid = threadIdx.x;
  if (tid < 64) sM[tid>>2][tid&3] = Mmat[(tid>>2)*12 + layer*4 + (tid&3)];
  if (tid < 4)  sC[tid] = cbias[layer*4 + tid];
  __syncthreads();
  int wid = tid >> 6, lane = tid & 63;
  int n = blockIdx.x*4 + wid;
  int nn = (n < N) ? n : 0;
  int r = row[nn];
  int deg = row[nn+1] - r;
  if (n >= N) deg = 0;
  float4 ad = *(const float4*)(a_dst + (size_t)nn*4);

  float al[4] = {-1e30f, -1e30f, -1e30f, -1e30f};
  float ae[4] = {0.f, 0.f, 0.f, 0.f};
  int mysrc = 0;
  if (lane < deg)
    edge_alpha_at(ecsr, r + lane, sM, sC, csr_src, a_src, ad, al, ae, &mysrc);
  float mx0 = al[0], mx1 = al[1], mx2 = al[2], mx3 = al[3];
  float s0 = ae[0], s1 = ae[1], s2 = ae[2], s3 = ae[3];
  for (int e = lane + 64; e < deg; e += 64){       // rare (deg>64)
    float al2[4], ae2[4]; int sr2;
    edge_alpha_at(ecsr, r + e, sM, sC, csr_src, a_src, ad, al2, ae2, &sr2);
    mx0 = fmaxf(mx0, al2[0]); mx1 = fmaxf(mx1, al2[1]);
    mx2 = fmaxf(mx2, al2[2]); mx3 = fmaxf(mx3, al2[3]);
    s0 += ae2[0]; s1 += ae2[1]; s2 += ae2[2]; s3 += ae2[3];
  }
  #pragma unroll
  for (int m = 1; m < 64; m <<= 1){
    mx0 = fmaxf(mx0, __shfl_xor(mx0,m)); mx1 = fmaxf(mx1, __shfl_xor(mx1,m));
    mx2 = fmaxf(mx2, __shfl_xor(mx2,m)); mx3 = fmaxf(mx3, __shfl_xor(mx3,m));
    s0 += __shfl_xor(s0,m); s1 += __shfl_xor(s1,m); s2 += __shfl_xor(s2,m); s3 += __shfl_xor(s3,m);
  }
  // self-loop: ae = mean of incoming ae (deg==0 -> ae = c, since mean edge_attr = 0)
  float invdeg = (deg > 0) ? 1.0f/(float)deg : 0.0f;
  float e0 = (deg > 0) ? s0*invdeg : sC[0];
  float e1 = (deg > 0) ? s1*invdeg : sC[1];
  float e2 = (deg > 0) ? s2*invdeg : sC[2];
  float e3 = (deg > 0) ? s3*invdeg : sC[3];
  float4 asn = *(const float4*)(a_src + (size_t)nn*4);
  float f0 = lrelu(asn.x + ad.x + e0);
  float f1 = lrelu(asn.y + ad.y + e1);
  float f2 = lrelu(asn.z + ad.z + e2);
  float f3 = lrelu(asn.w + ad.w + e3);
  mx0 = fmaxf(mx0,f0); mx1 = fmaxf(mx1,f1); mx2 = fmaxf(mx2,f2); mx3 = fmaxf(mx3,f3);

  float p0 = 0.f, p1 = 0.f, p2 = 0.f, p3 = 0.f;
  if (lane < deg){
    p0 = expg(al[0]-mx0); p1 = expg(al[1]-mx1);
    p2 = expg(al[2]-mx2); p3 = expg(al[3]-mx3);
  }
  sP[wid][0][lane] = p0; sP[wid][1][lane] = p1;
  sP[wid][2][lane] = p2; sP[wid][3][lane] = p3;
  sOff[wid][lane] = mysrc << 8;   // src * 256 bytes (bf16 row)
  float d0 = p0, d1 = p1, d2 = p2, d3 = p3;
  for (int e = lane + 64; e < deg; e += 64){       // rare
    float al2[4], ae2[4]; int sr2;
    edge_alpha_at(ecsr, r + e, sM, sC, csr_src, a_src, ad, al2, ae2, &sr2);
    d0 += expg(al2[0]-mx0); d1 += expg(al2[1]-mx1);
    d2 += expg(al2[2]-mx2); d3 += expg(al2[3]-mx3);
  }
  #pragma unroll
  for (int m = 1; m < 64; m <<= 1){
    d0 += __shfl_xor(d0,m); d1 += __shfl_xor(d1,m); d2 += __shfl_xor(d2,m); d3 += __shfl_xor(d3,m);
  }
  float ps0 = expg(f0-mx0), ps1 = expg(f1-mx1), ps2 = expg(f2-mx2), ps3 = expg(f3-mx3);
  float i0 = 1.0f/(d0+ps0+1e-16f), i1 = 1.0f/(d1+ps1+1e-16f);
  float i2 = 1.0f/(d2+ps2+1e-16f), i3 = 1.0f/(d3+ps3+1e-16f);

  // gather: lane covers channels 2*lane, 2*lane+1; head h = lane>>4
  int h = lane >> 4;
  float psh = h==0 ? ps0 : h==1 ? ps1 : h==2 ? ps2 : ps3;
  float ih  = h==0 ? i0  : h==1 ? i1  : h==2 ? i2  : i3;
  float mxh = h==0 ? mx0 : h==1 ? mx1 : h==2 ? mx2 : mx3;
  const char* xb = (const char*)xh;
  float acc0 = 0.f, acc1 = 0.f;
  int dmin = deg < 64 ? deg : 64;
  int e = 0;
  for (; e + 4 <= dmin; e += 4){
    int oA = sOff[wid][e+0], oB = sOff[wid][e+1], oC = sOff[wid][e+2], oD = sOff[wid][e+3];
    float qA = sP[wid][h][e+0], qB = sP[wid][h][e+1];
    float qC = sP[wid][h][e+2], qD = sP[wid][h][e+3];
    ushort2 xA = *(const ushort2*)(xb + (size_t)oA + lane*4);
    ushort2 xB = *(const ushort2*)(xb + (size_t)oB + lane*4);
    ushort2 xC = *(const ushort2*)(xb + (size_t)oC + lane*4);
    ushort2 xD = *(const ushort2*)(xb + (size_t)oD + lane*4);
    acc0 += qA*bf2f(xA.x) + qB*bf2f(xB.x) + qC*bf2f(xC.x) + qD*bf2f(xD.x);
    acc1 += qA*bf2f(xA.y) + qB*bf2f(xB.y) + qC*bf2f(xC.y) + qD*bf2f(xD.y);
  }
  for (; e < dmin; ++e){
    int o = sOff[wid][e];
    float q = sP[wid][h][e];
    ushort2 xv = *(const ushort2*)(xb + (size_t)o + lane*4);
    acc0 += q*bf2f(xv.x); acc1 += q*bf2f(xv.y);
  }
  for (; e < deg; ++e){            // rare (deg>64): recompute
    float al2[4], ae2[4]; int sr2;
    edge_alpha_at(ecsr, r + e, sM, sC, csr_src, a_src, ad, al2, ae2, &sr2);
    float av = h==0 ? al2[0] : h==1 ? al2[1] : h==2 ? al2[2] : al2[3];
    float q = expg(av - mxh);
    ushort2 xv = *(const ushort2*)(xb + (size_t)sr2*256 + lane*4);
    acc0 += q*bf2f(xv.x); acc1 += q*bf2f(xv.y);
  }
  if (n < N){
    ushort2 xn = *(const ushort2*)(xb + (size_t)nn*256 + lane*4);
    acc0 += psh * bf2f(xn.x);
    acc1 += psh * bf2f(xn.y);
    float2 bc = *(const float2*)(bconv + layer*128 + 2*lane);
    acc0 = acc0*ih + bc.x;
    acc1 = acc1*ih + bc.y;
    float2 o; o.x = acc0; o.y = acc1;
    *(float2*)(hout + (size_t)nn*128 + 2*lane) = o;
  }
}

// ---------------- batch norm ----------------
__global__ __launch_bounds__(256) void bn_stats(const float* __restrict__ h, float* __restrict__ sum,
                                                float* __restrict__ sq, int N){
  int c = threadIdx.x & 127;
  int sub = threadIdx.x >> 7;
  float s = 0.f, q = 0.f;
  for (int n = blockIdx.x*2 + sub; n < N; n += gridDim.x*2){
    float v = h[(size_t)n*128 + c];
    s += v; q += v*v;
  }
  __shared__ float ls[256], lq[256];
  ls[threadIdx.x] = s; lq[threadIdx.x] = q;
  __syncthreads();
  if (threadIdx.x < 128){
    s = ls[threadIdx.x] + ls[threadIdx.x + 128];
    q = lq[threadIdx.x] + lq[threadIdx.x + 128];
    atomicAdd(&sum[c], s);
    atomicAdd(&sq[c], q);
  }
}
__global__ void bn_final(const float* __restrict__ sum, const float* __restrict__ sq,
                         const float* __restrict__ gamma, const float* __restrict__ beta,
                         float* __restrict__ scale, float* __restrict__ shift, int N){
  int c = threadIdx.x;
  float mean = sum[c] / (float)N;
  float var  = sq[c] / (float)N - mean*mean;
  var = fmaxf(var, 0.f);
  float rstd = rsqrtf(var + 1e-5f);
  float sc = gamma[c] * rstd;
  scale[c] = sc;
  shift[c] = beta[c] - mean*sc;
}
// BN + ReLU + residual; dual write: fp32 (residual stream) + bf16 (next GEMM input)
__global__ __launch_bounds__(256) void bn_elem(float* __restrict__ hg, const float* __restrict__ hprev,
                                               const float* __restrict__ scale, const float* __restrict__ shift,
                                               unsigned short* __restrict__ hbf, int total4){
  int i = blockIdx.x*256 + threadIdx.x;
  if (i >= total4) return;
  int c = (i*4) & 127;
  float4 v  = ((const float4*)hg)[i];
  float4 pv = ((const float4*)hprev)[i];
  float4 sc = *(const float4*)(scale + c);
  float4 sh = *(const float4*)(shift + c);
  float r0 = v.x*sc.x + sh.x; r0 = r0 > 0.f ? r0 : 0.f; r0 += pv.x;
  float r1 = v.y*sc.y + sh.y; r1 = r1 > 0.f ? r1 : 0.f; r1 += pv.y;
  float r2 = v.z*sc.z + sh.z; r2 = r2 > 0.f ? r2 : 0.f; r2 += pv.z;
  float r3 = v.w*sc.w + sh.w; r3 = r3 > 0.f ? r3 : 0.f; r3 += pv.w;
  float4 o; o.x = r0; o.y = r1; o.z = r2; o.w = r3;
  ((float4*)hg)[i] = o;
  ushort4 ob; ob.x = f2bf(r0); ob.y = f2bf(r1); ob.z = f2bf(r2); ob.w = f2bf(r3);
  ((ushort4*)hbf)[i] = ob;
}

// ---------------- host ----------------
extern "C" void kernel_launch(void* const* d_in, const int* in_sizes, int n_in,
                              void* d_out, int out_size, void* d_ws, size_t ws_size,
                              hipStream_t stream)
{
  const void* x        = d_in[0];
  const int*  ei       = (const int*)d_in[1];
  const void* eattr    = d_in[2];
  int N = in_sizes[0] / 64;
  int E = in_sizes[1] / 2;

  char* p = (char*)d_ws;
  auto alloc = [&](size_t bytes)->char* {
    char* r = p; p += (bytes + 255) & ~(size_t)255; return r;
  };
  // zero-region first (one memset)
  int*   deg    = (int*)alloc((size_t)N*4);
  int*   cursor = (int*)alloc((size_t)N*4);
  float* bnsum  = (float*)alloc(3*128*4);
  float* bnsq   = (float*)alloc(3*128*4);
  size_t zbytes = (size_t)(p - (char*)deg);
  int*   dflag  = (int*)alloc(256);
  int*   row    = (int*)alloc(((size_t)N + 1)*4);
  int*   part   = (int*)alloc(1024*4);
  int*   csr_src= (int*)alloc((size_t)E*4);
  int*   csr_eid= (int*)alloc((size_t)E*4);
  unsigned short* ecsr = (unsigned short*)alloc((size_t)E*16*2);
  float* hA     = (float*)alloc((size_t)N*128*4);
  float* hB     = (float*)alloc((size_t)N*128*4);
  unsigned short* hAb = (unsigned short*)alloc((size_t)N*128*2);
  unsigned short* hBb = (unsigned short*)alloc((size_t)N*128*2);
  unsigned short* xhb = (unsigned short*)alloc((size_t)N*128*2);
  float* a_src  = (float*)alloc((size_t)N*4*4);
  float* a_dst  = (float*)alloc((size_t)N*4*4);
  float* Mmat   = (float*)alloc(16*12*4);
  float* cbias  = (float*)alloc(12*4);
  float* bnscale= (float*)alloc(128*4);
  float* bnshift= (float*)alloc(128*4);
  unsigned short* xc  = (unsigned short*)alloc((size_t)N*64*2);
  float* wc     = (float*)alloc(130000*4);

  // canonical weight buffers (fp32)
  int   woff[14] = {0, 8192, 8320, 10368, 10496, 59648, 108800, 109184,
                    109568, 109952, 110336, 110720, 111104, 127488};
  int   wcnt[14] = {8192, 128, 2048, 128, 49152, 49152, 384, 384, 384, 384, 384, 384, 16384, 128};
  CvList L; L.n = 14;
  for (int a = 0; a < 14; ++a){ L.src[a] = d_in[3+a]; L.dst[a] = wc + woff[a]; L.cnt[a] = wcnt[a]; }
  float* cW_atom = wc + woff[0];  float* cb_atom = wc + woff[1];
  float* cW_bond = wc + woff[2];  float* cb_bond = wc + woff[3];
  float* cW_lin  = wc + woff[4];  float* cW_edge = wc + woff[5];
  float* catt_s  = wc + woff[6];  float* catt_d  = wc + woff[7];
  float* catt_e  = wc + woff[8];  float* cbconv  = wc + woff[9];
  float* cgamma  = wc + woff[10]; float* cbeta   = wc + woff[11];
  float* cW_out  = wc + woff[12]; float* cb_out  = wc + woff[13];

  hipMemsetAsync(deg, 0, zbytes, stream);
  detect_dtype<<<1, 64, 0, stream>>>((const unsigned short*)x, dflag);
  conv_weights<<<64, 256, 0, stream>>>(L, dflag);
  conv_bf16<<<(N*16 + 255)/256, 256, 0, stream>>>(x, xc, N*16, dflag);

  precompute_M<<<1, 256, 0, stream>>>(cW_edge, catt_e, cW_bond, cb_bond, Mmat, cbias);
  deg_count<<<(E + 255)/256, 256, 0, stream>>>(ei, E, deg);
  int P = (N + 1023)/1024;
  scan_part<<<P, 256, 0, stream>>>(deg, part, N);
  scan_top<<<1, 64, 0, stream>>>(part, P);
  scan_write<<<P, 256, 0, stream>>>(deg, part, row, N, E);
  csr_fill<<<(E + 255)/256, 256, 0, stream>>>(ei, E, row, cursor, csr_src, csr_eid);
  gather_eattr<<<(E + 255)/256, 256, 0, stream>>>(eattr, csr_eid, ecsr, E, dflag);

  // atom embedding: hA(fp32) + hAb(bf16) = x @ W_atom + b_atom
  mfma_lin<64, 2><<<(N + 63)/64, 256, 0, stream>>>(xc, cW_atom, cb_atom, hA, hAb, N, dflag);

  float* cur = hA; float* oth = hB;
  unsigned short* curb = hAb; unsigned short* othb = hBb;
  for (int l = 0; l < 3; ++l){
    mfma_lin<128, 0><<<(N + 63)/64, 256, 0, stream>>>(curb, cW_lin + (size_t)l*16384, nullptr, xhb, nullptr, N, dflag);
    att_scores<<<(N*4 + 255)/256, 256, 0, stream>>>(xhb, catt_s + l*128, catt_d + l*128, a_src, a_dst, N);
    gat_agg<<<(N + 3)/4, 256, 0, stream>>>(xhb, ecsr, csr_src, row, a_src, a_dst,
                                           Mmat, cbias, cbconv, oth, N, l);
    bn_stats<<<256, 256, 0, stream>>>(oth, bnsum + l*128, bnsq + l*128, N);
    bn_final<<<1, 128, 0, stream>>>(bnsum + l*128, bnsq + l*128, cgamma + l*128, cbeta + l*128,
                                    bnscale, bnshift, N);
    bn_elem<<<((N*128/4) + 255)/256, 256, 0, stream>>>(oth, cur, bnscale, bnshift, othb, N*128/4);
    float* t = cur; cur = oth; oth = t;
    unsigned short* tb = curb; curb = othb; othb = tb;
  }
  // final projection, output dtype per detected storage
  mfma_lin<128, 1><<<(N + 63)/64, 256, 0, stream>>>(curb, cW_out, cb_out, d_out, nullptr, N, dflag);
}

// Round 5
// 641.479 us; speedup vs baseline: 1.1894x; 1.1894x over previous
//
#include <hip/hip_runtime.h>
#include <stdint.h>

#define HID 128

typedef __attribute__((ext_vector_type(8))) short bf16x8;
typedef __attribute__((ext_vector_type(4))) float f32x4;

__device__ __forceinline__ float bf2f(unsigned short u){
  union { unsigned int i; float f; } x; x.i = ((unsigned int)u) << 16; return x.f;
}
__device__ __forceinline__ unsigned short f2bf(float f){
  union { float f; unsigned int i; } x; x.f = f;
  unsigned int b = x.i;
  return (unsigned short)((b + 0x7fffu + ((b >> 16) & 1u)) >> 16);
}

// ---------------- dtype detection (parallel): fp32 storage (1) vs bf16 (0) ----------------
__global__ void detect_dtype(const unsigned short* __restrict__ x, int* __restrict__ flag){
  int tid = threadIdx.x;   // 256 threads
  unsigned short u = x[tid];
  int ex = (u >> 7) & 0xFF;
  int z = ((tid & 1) == 0 && u == 0) ? 1 : 0;
  int b = (ex >= 140) ? 1 : 0;
  __shared__ int sz[256], sb[256];
  sz[tid] = z; sb[tid] = b;
  __syncthreads();
  for (int m = 128; m > 0; m >>= 1){
    if (tid < m){ sz[tid] += sz[tid + m]; sb[tid] += sb[tid + m]; }
    __syncthreads();
  }
  if (tid == 0) flag[0] = (sz[0] >= 32 || sb[0] >= 8) ? 1 : 0;
}

// ---------------- canonicalization ----------------
struct CvList {
  const void* src[16];
  float* dst[16];
  int cnt[16];
  int n;
};
__global__ __launch_bounds__(256) void conv_weights(CvList L, const int* __restrict__ flag){
  bool isf32 = flag[0] != 0;
  for (int a = 0; a < L.n; ++a){
    const void* s = L.src[a];
    float* d = L.dst[a];
    int c = L.cnt[a];
    for (int i = blockIdx.x*256 + threadIdx.x; i < c; i += gridDim.x*256){
      d[i] = isf32 ? ((const float*)s)[i] : bf2f(((const unsigned short*)s)[i]);
    }
  }
}
__global__ __launch_bounds__(256) void conv_bf16(const void* __restrict__ src,
                                                 unsigned short* __restrict__ dst,
                                                 int n4, const int* __restrict__ flag){
  int i = blockIdx.x*256 + threadIdx.x;
  if (i >= n4) return;
  if (flag[0]){
    float4 v = ((const float4*)src)[i];
    ushort4 o; o.x = f2bf(v.x); o.y = f2bf(v.y); o.z = f2bf(v.z); o.w = f2bf(v.w);
    ((ushort4*)dst)[i] = o;
  } else {
    ((ushort4*)dst)[i] = ((const ushort4*)src)[i];
  }
}

// ---------------- precompute M = W_bond @ (W_edge @ att_edge), cbias = b_bond @ ve ----
__global__ __launch_bounds__(256) void precompute_M(
    const float* __restrict__ We, const float* __restrict__ ae,
    const float* __restrict__ Wb, const float* __restrict__ bb,
    float* __restrict__ Mout, float* __restrict__ cb)
{
  __shared__ float ve[128*12];
  int tid = threadIdx.x;
  for (int i = tid; i < 128*12; i += 256){
    int c = i / 12, lh = i % 12; int l = lh >> 2, h = lh & 3;
    float s = 0.f;
    for (int d = 0; d < 32; ++d)
      s += We[l*16384 + c*128 + h*32 + d] * ae[l*128 + h*32 + d];
    ve[i] = s;
  }
  __syncthreads();
  for (int i = tid; i < 16*12; i += 256){
    int k = i / 12, lh = i % 12;
    float s = 0.f;
    for (int c = 0; c < 128; ++c) s += Wb[k*128 + c] * ve[c*12 + lh];
    Mout[i] = s;
  }
  for (int i = tid; i < 12; i += 256){
    float s = 0.f;
    for (int c = 0; c < 128; ++c) s += bb[c] * ve[c*12 + i];
    cb[i] = s;
  }
}

// ---------------- CSR build ----------------
__global__ __launch_bounds__(256) void deg_count(const int* __restrict__ ei, int E, int* __restrict__ deg){
  int e = blockIdx.x*256 + threadIdx.x;
  if (e < E) atomicAdd(&deg[ei[E + e]], 1);
}
__global__ __launch_bounds__(256) void scan_part(const int* __restrict__ deg, int* __restrict__ part, int N){
  int base = blockIdx.x*1024;
  int s = 0;
  for (int i = threadIdx.x; i < 1024; i += 256){ int j = base + i; if (j < N) s += deg[j]; }
  __shared__ int sh[256];
  sh[threadIdx.x] = s; __syncthreads();
  for (int m = 128; m > 0; m >>= 1){ if (threadIdx.x < m) sh[threadIdx.x] += sh[threadIdx.x + m]; __syncthreads(); }
  if (threadIdx.x == 0) part[blockIdx.x] = sh[0];
}
__global__ void scan_top(int* part, int P){
  if (threadIdx.x == 0 && blockIdx.x == 0){
    int acc = 0;
    for (int i = 0; i < P; ++i){ int v = part[i]; part[i] = acc; acc += v; }
  }
}
__global__ __launch_bounds__(256) void scan_write(const int* __restrict__ deg, const int* __restrict__ part,
                                                  int* __restrict__ row, int N, int E){
  int base = blockIdx.x*1024 + threadIdx.x*4;
  int v0=0,v1=0,v2=0,v3=0;
  if (base+0 < N) v0 = deg[base+0];
  if (base+1 < N) v1 = deg[base+1];
  if (base+2 < N) v2 = deg[base+2];
  if (base+3 < N) v3 = deg[base+3];
  int s = v0+v1+v2+v3;
  __shared__ int sh[256];
  sh[threadIdx.x] = s; __syncthreads();
  for (int m = 1; m < 256; m <<= 1){
    int t = (threadIdx.x >= m) ? sh[threadIdx.x - m] : 0;
    __syncthreads();
    sh[threadIdx.x] += t;
    __syncthreads();
  }
  int excl = sh[threadIdx.x] - s + part[blockIdx.x];
  if (base+0 < N) row[base+0] = excl; excl += v0;
  if (base+1 < N) row[base+1] = excl; excl += v1;
  if (base+2 < N) row[base+2] = excl; excl += v2;
  if (base+3 < N) row[base+3] = excl;
  if (blockIdx.x == 0 && threadIdx.x == 0) row[N] = E;
}
__global__ __launch_bounds__(256) void csr_fill(const int* __restrict__ ei, int E, const int* __restrict__ row,
                                                int* __restrict__ cursor, int* __restrict__ csr_src,
                                                int* __restrict__ csr_eid, int* __restrict__ csr_dst){
  int e = blockIdx.x*256 + threadIdx.x;
  if (e >= E) return;
  int s = ei[e], d = ei[E + e];
  int pos = atomicAdd(&cursor[d], 1);
  int idx = row[d] + pos;
  csr_src[idx] = s;
  csr_eid[idx] = e;
  csr_dst[idx] = d;
}
// gather edge_attr into CSR order (bf16), once — layer-invariant
__global__ __launch_bounds__(256) void gather_eattr(const void* __restrict__ eattr,
                                                    const int* __restrict__ csr_eid,
                                                    unsigned short* __restrict__ ecsr,
                                                    int E, const int* __restrict__ flag){
  int pos = blockIdx.x*256 + threadIdx.x;
  if (pos >= E) return;
  int eid = csr_eid[pos];
  uint4 o0, o1;
  if (flag[0]){
    const float4* pp = (const float4*)((const float*)eattr + (size_t)eid*16);
    float4 a = pp[0], b = pp[1], c = pp[2], d = pp[3];
    o0.x = f2bf(a.x) | ((unsigned)f2bf(a.y) << 16);
    o0.y = f2bf(a.z) | ((unsigned)f2bf(a.w) << 16);
    o0.z = f2bf(b.x) | ((unsigned)f2bf(b.y) << 16);
    o0.w = f2bf(b.z) | ((unsigned)f2bf(b.w) << 16);
    o1.x = f2bf(c.x) | ((unsigned)f2bf(c.y) << 16);
    o1.y = f2bf(c.z) | ((unsigned)f2bf(c.w) << 16);
    o1.z = f2bf(d.x) | ((unsigned)f2bf(d.y) << 16);
    o1.w = f2bf(d.z) | ((unsigned)f2bf(d.w) << 16);
  } else {
    const uint4* pp = (const uint4*)((const unsigned short*)eattr + (size_t)eid*16);
    o0 = pp[0]; o1 = pp[1];
  }
  uint4* op = (uint4*)(ecsr + (size_t)pos*16);
  op[0] = o0; op[1] = o1;
}
// per-node mean of CSR-ordered edge_attr (layer-invariant), + deg indicator
__global__ __launch_bounds__(256) void ea_mean_k(const unsigned short* __restrict__ ecsr,
                                                 const int* __restrict__ row,
                                                 float* __restrict__ ea_mean,
                                                 float* __restrict__ deg_ind, int N){
  int idx = blockIdx.x*256 + threadIdx.x;
  if (idx >= N*4) return;
  int n = idx >> 2, q = idx & 3;
  int r = row[n], deg = row[n+1] - r;
  float s0=0.f, s1=0.f, s2=0.f, s3=0.f;
  for (int e = 0; e < deg; ++e){
    ushort4 u = *(const ushort4*)(ecsr + (size_t)(r+e)*16 + q*4);
    s0 += bf2f(u.x); s1 += bf2f(u.y); s2 += bf2f(u.z); s3 += bf2f(u.w);
  }
  float inv = 1.f / (float)(deg > 0 ? deg : 1);
  float4 o; o.x = s0*inv; o.y = s1*inv; o.z = s2*inv; o.w = s3*inv;
  *(float4*)(ea_mean + (size_t)n*16 + q*4) = o;
  if (q == 0) deg_ind[n] = (deg > 0) ? 1.f : 0.f;
}

__device__ __forceinline__ float lrelu(float x){ return x > 0.f ? x : 0.2f*x; }
__device__ __forceinline__ float expg(float x){ return __expf(fminf(x, 0.f)); }

// ---------------- MFMA GEMM: out[N,128] = A[N,K](bf16) @ W[K,128] (+bias) ----------------
// OUTMODE: 0 = bf16 out, 1 = external out (flag: 1=fp32, 0=bf16), 2 = dual fp32 + bf16
// EPI: fused att-score + self-loop-alpha epilogue
template<int K, int OUTMODE, bool EPI>
__global__ __launch_bounds__(256) void mfma_lin(const unsigned short* __restrict__ A,
                                                const float* __restrict__ W,
                                                const float* __restrict__ bias,
                                                void* __restrict__ Out, void* __restrict__ Out2,
                                                int N, const int* __restrict__ flag,
                                                const float* __restrict__ attS,
                                                const float* __restrict__ attD,
                                                const float* __restrict__ Ml,   // Mmat + layer*4, stride 12
                                                const float* __restrict__ cbl,  // cbias + layer*4
                                                const float* __restrict__ ea_mean,
                                                const float* __restrict__ deg_ind,
                                                float* __restrict__ a_src,
                                                float* __restrict__ a_dst,
                                                float* __restrict__ alpha_self)
{
  constexpr int KP = K + 8;
  __shared__ unsigned short WT[128*KP];
  __shared__ float sAs[128], sAd[128];
  __shared__ float sMM[16][4];
  __shared__ float sCB[4];
  int tid = threadIdx.x;
  for (int i = tid; i < K*128; i += 256){
    int k = i >> 7, ch = i & 127;
    WT[ch*KP + k] = f2bf(W[i]);
  }
  if (EPI){
    if (tid < 128){ sAs[tid] = attS[tid]; sAd[tid] = attD[tid]; }
    if (tid < 64) sMM[tid>>2][tid&3] = Ml[(tid>>2)*12 + (tid&3)];
    if (tid < 4)  sCB[tid] = cbl[tid];
  }
  __syncthreads();
  int wid = tid >> 6, lane = tid & 63;
  int quad = lane >> 4, m = lane & 15;
  int nodeBase = blockIdx.x*64 + wid*16;
  int node = nodeBase + m;
  int nodeC = (node < N) ? node : 0;
  bf16x8 afr[K/32];
  #pragma unroll
  for (int kb = 0; kb < K/32; ++kb)
    afr[kb] = *(const bf16x8*)(A + (size_t)nodeC*K + kb*32 + quad*8);
  f32x4 acc[8] = {};
  #pragma unroll
  for (int t = 0; t < 8; ++t){
    #pragma unroll
    for (int kb = 0; kb < K/32; ++kb){
      bf16x8 bfr = *(const bf16x8*)&WT[(t*16 + m)*KP + kb*32 + quad*8];
      acc[t] = __builtin_amdgcn_mfma_f32_16x16x32_bf16(afr[kb], bfr, acc[t], 0, 0, 0);
    }
  }
  bool f32out = (OUTMODE == 1) && (flag[0] != 0);
  #pragma unroll
  for (int t = 0; t < 8; ++t){
    int ch = t*16 + m;
    float bv = bias ? bias[ch] : 0.f;
    #pragma unroll
    for (int r2 = 0; r2 < 4; ++r2){
      int nd = nodeBase + quad*4 + r2;
      if (nd < N){
        float v = acc[t][r2] + bv;
        if (OUTMODE == 0){
          ((unsigned short*)Out)[(size_t)nd*HID + ch] = f2bf(v);
        } else if (OUTMODE == 2){
          ((float*)Out)[(size_t)nd*HID + ch] = v;
          ((unsigned short*)Out2)[(size_t)nd*HID + ch] = f2bf(v);
        } else {
          if (f32out) ((float*)Out)[(size_t)nd*HID + ch] = v;
          else        ((unsigned short*)Out)[(size_t)nd*HID + ch] = f2bf(v);
        }
      }
    }
  }
  if (EPI){
    // per node (row): a_src[n][h] = sum_c xh[n][c]*attS[c], head h = ch in [32h,32h+32)
    #pragma unroll
    for (int r2 = 0; r2 < 4; ++r2){
      float vs[4], vd[4];
      #pragma unroll
      for (int h = 0; h < 4; ++h){
        int c0 = (2*h)*16 + m, c1 = (2*h+1)*16 + m;
        vs[h] = acc[2*h][r2]*sAs[c0] + acc[2*h+1][r2]*sAs[c1];
        vd[h] = acc[2*h][r2]*sAd[c0] + acc[2*h+1][r2]*sAd[c1];
      }
      #pragma unroll
      for (int mm = 1; mm < 16; mm <<= 1){
        #pragma unroll
        for (int h = 0; h < 4; ++h){
          vs[h] += __shfl_xor(vs[h], mm);
          vd[h] += __shfl_xor(vd[h], mm);
        }
      }
      if (m == 0){
        int nd = nodeBase + quad*4 + r2;
        if (nd < N){
          float ci = deg_ind[nd];
          const float4* em = (const float4*)(ea_mean + (size_t)nd*16);
          float4 e0 = em[0], e1 = em[1], e2 = em[2], e3 = em[3];
          float ev[16] = {e0.x,e0.y,e0.z,e0.w, e1.x,e1.y,e1.z,e1.w,
                          e2.x,e2.y,e2.z,e2.w, e3.x,e3.y,e3.z,e3.w};
          float4 vsv, vdv, asv;
          float aS[4];
          #pragma unroll
          for (int h = 0; h < 4; ++h){
            float d = sCB[h]*ci;
            #pragma unroll
            for (int k = 0; k < 16; ++k) d += ev[k]*sMM[k][h];
            aS[h] = lrelu(vs[h] + vd[h] + d);
          }
          vsv.x=vs[0]; vsv.y=vs[1]; vsv.z=vs[2]; vsv.w=vs[3];
          vdv.x=vd[0]; vdv.y=vd[1]; vdv.z=vd[2]; vdv.w=vd[3];
          asv.x=aS[0]; asv.y=aS[1]; asv.z=aS[2]; asv.w=aS[3];
          *(float4*)(a_src + (size_t)nd*4) = vsv;
          *(float4*)(a_dst + (size_t)nd*4) = vdv;
          *(float4*)(alpha_self + (size_t)nd*4) = asv;
        }
      }
    }
  }
}

// ---------------- edge-parallel alpha (CSR order, coalesced ecsr) ----------------
__global__ __launch_bounds__(256) void edge_alpha(
    const unsigned short* __restrict__ ecsr,
    const int* __restrict__ csr_src, const int* __restrict__ csr_dst,
    const float* __restrict__ a_src, const float* __restrict__ a_dst,
    const float* __restrict__ Mmat, const float* __restrict__ cbias,
    float4* __restrict__ alphaA, int E, int layer)
{
  __shared__ float sM[16][4];
  __shared__ float sC[4];
  int tid = threadIdx.x;
  if (tid < 64) sM[tid>>2][tid&3] = Mmat[(tid>>2)*12 + layer*4 + (tid&3)];
  if (tid < 4)  sC[tid] = cbias[layer*4 + tid];
  __syncthreads();
  int pos = blockIdx.x*256 + tid;
  if (pos >= E) return;
  int src = csr_src[pos], dst = csr_dst[pos];
  const uint4* ep = (const uint4*)(ecsr + (size_t)pos*16);
  uint4 u0 = ep[0], u1 = ep[1];
  unsigned w[8] = {u0.x,u0.y,u0.z,u0.w,u1.x,u1.y,u1.z,u1.w};
  float a0 = sC[0], a1 = sC[1], a2 = sC[2], a3 = sC[3];
  #pragma unroll
  for (int k = 0; k < 16; ++k){
    float v = bf2f((unsigned short)((k & 1) ? (w[k>>1] >> 16) : (w[k>>1] & 0xffffu)));
    a0 += v*sM[k][0]; a1 += v*sM[k][1]; a2 += v*sM[k][2]; a3 += v*sM[k][3];
  }
  float4 as4 = *(const float4*)(a_src + (size_t)src*4);
  float4 ad4 = *(const float4*)(a_dst + (size_t)dst*4);
  float4 al;
  al.x = lrelu(as4.x + ad4.x + a0);
  al.y = lrelu(as4.y + ad4.y + a1);
  al.z = lrelu(as4.z + ad4.z + a2);
  al.w = lrelu(as4.w + ad4.w + a3);
  alphaA[pos] = al;
}

// ---------------- GAT aggregation v4: wave/node, contiguous alpha, bf16 gathers ----
__global__ __launch_bounds__(256) void gat_agg(
    const unsigned short* __restrict__ xh, const float4* __restrict__ alphaA,
    const int* __restrict__ csr_src, const int* __restrict__ row,
    const float4* __restrict__ alpha_self,
    const float* __restrict__ bconv, float* __restrict__ hout, int N, int layer)
{
  __shared__ float sPf[4][256];   // [wave][e*4+h]  (conflict-free reads)
  __shared__ int   sOff[4][64];
  int tid = threadIdx.x;
  int wid = tid >> 6, lane = tid & 63;
  int n = blockIdx.x*4 + wid;
  int nn = (n < N) ? n : 0;
  int r = row[nn];
  int deg = row[nn+1] - r;
  if (n >= N) deg = 0;

  float4 aL; aL.x = aL.y = aL.z = aL.w = -1e30f;
  int mysrc = 0;
  if (lane < deg){
    aL = alphaA[r + lane];
    mysrc = csr_src[r + lane];
  }
  float mx0 = aL.x, mx1 = aL.y, mx2 = aL.z, mx3 = aL.w;
  for (int e = lane + 64; e < deg; e += 64){   // rare
    float4 t = alphaA[r + e];
    mx0 = fmaxf(mx0, t.x); mx1 = fmaxf(mx1, t.y);
    mx2 = fmaxf(mx2, t.z); mx3 = fmaxf(mx3, t.w);
  }
  #pragma unroll
  for (int m = 1; m < 64; m <<= 1){
    mx0 = fmaxf(mx0, __shfl_xor(mx0,m)); mx1 = fmaxf(mx1, __shfl_xor(mx1,m));
    mx2 = fmaxf(mx2, __shfl_xor(mx2,m)); mx3 = fmaxf(mx3, __shfl_xor(mx3,m));
  }
  float4 sf = alpha_self[nn];
  mx0 = fmaxf(mx0, sf.x); mx1 = fmaxf(mx1, sf.y);
  mx2 = fmaxf(mx2, sf.z); mx3 = fmaxf(mx3, sf.w);

  float p0 = 0.f, p1 = 0.f, p2 = 0.f, p3 = 0.f;
  if (lane < deg){
    p0 = expg(aL.x-mx0); p1 = expg(aL.y-mx1);
    p2 = expg(aL.z-mx2); p3 = expg(aL.w-mx3);
  }
  float4 pv; pv.x = p0; pv.y = p1; pv.z = p2; pv.w = p3;
  *(float4*)&sPf[wid][lane*4] = pv;
  sOff[wid][lane] = mysrc << 8;   // src * 256 B (bf16 row)
  float d0 = p0, d1 = p1, d2 = p2, d3 = p3;
  for (int e = lane + 64; e < deg; e += 64){   // rare
    float4 t = alphaA[r + e];
    d0 += expg(t.x-mx0); d1 += expg(t.y-mx1);
    d2 += expg(t.z-mx2); d3 += expg(t.w-mx3);
  }
  #pragma unroll
  for (int m = 1; m < 64; m <<= 1){
    d0 += __shfl_xor(d0,m); d1 += __shfl_xor(d1,m); d2 += __shfl_xor(d2,m); d3 += __shfl_xor(d3,m);
  }
  float ps0 = expg(sf.x-mx0), ps1 = expg(sf.y-mx1), ps2 = expg(sf.z-mx2), ps3 = expg(sf.w-mx3);
  float i0 = 1.0f/(d0+ps0+1e-16f), i1 = 1.0f/(d1+ps1+1e-16f);
  float i2 = 1.0f/(d2+ps2+1e-16f), i3 = 1.0f/(d3+ps3+1e-16f);

  // gather: lane covers channels 2*lane, 2*lane+1; head h = lane>>4
  int h = lane >> 4;
  float psh = h==0 ? ps0 : h==1 ? ps1 : h==2 ? ps2 : ps3;
  float ih  = h==0 ? i0  : h==1 ? i1  : h==2 ? i2  : i3;
  float mxh = h==0 ? mx0 : h==1 ? mx1 : h==2 ? mx2 : mx3;
  const char* xb = (const char*)xh;
  float acc0 = 0.f, acc1 = 0.f;
  int dmin = deg < 64 ? deg : 64;
  int e = 0;
  for (; e + 4 <= dmin; e += 4){
    int oA = sOff[wid][e+0], oB = sOff[wid][e+1], oC = sOff[wid][e+2], oD = sOff[wid][e+3];
    float qA = sPf[wid][(e+0)*4 + h], qB = sPf[wid][(e+1)*4 + h];
    float qC = sPf[wid][(e+2)*4 + h], qD = sPf[wid][(e+3)*4 + h];
    ushort2 xA = *(const ushort2*)(xb + (size_t)oA + lane*4);
    ushort2 xB = *(const ushort2*)(xb + (size_t)oB + lane*4);
    ushort2 xC = *(const ushort2*)(xb + (size_t)oC + lane*4);
    ushort2 xD = *(const ushort2*)(xb + (size_t)oD + lane*4);
    acc0 += qA*bf2f(xA.x) + qB*bf2f(xB.x) + qC*bf2f(xC.x) + qD*bf2f(xD.x);
    acc1 += qA*bf2f(xA.y) + qB*bf2f(xB.y) + qC*bf2f(xC.y) + qD*bf2f(xD.y);
  }
  for (; e < dmin; ++e){
    int o = sOff[wid][e];
    float q = sPf[wid][e*4 + h];
    ushort2 xv = *(const ushort2*)(xb + (size_t)o + lane*4);
    acc0 += q*bf2f(xv.x); acc1 += q*bf2f(xv.y);
  }
  for (; e < deg; ++e){            // rare (deg>64)
    float4 t = alphaA[r + e];
    float av = h==0 ? t.x : h==1 ? t.y : h==2 ? t.z : t.w;
    float q = expg(av - mxh);
    int s = csr_src[r + e];
    ushort2 xv = *(const ushort2*)(xb + (size_t)s*256 + lane*4);
    acc0 += q*bf2f(xv.x); acc1 += q*bf2f(xv.y);
  }
  if (n < N){
    ushort2 xn = *(const ushort2*)(xb + (size_t)nn*256 + lane*4);
    acc0 += psh * bf2f(xn.x);
    acc1 += psh * bf2f(xn.y);
    float2 bc = *(const float2*)(bconv + layer*128 + 2*lane);
    acc0 = acc0*ih + bc.x;
    acc1 = acc1*ih + bc.y;
    float2 o; o.x = acc0; o.y = acc1;
    *(float2*)(hout + (size_t)nn*128 + 2*lane) = o;
  }
}

// ---------------- batch norm ----------------
__global__ __launch_bounds__(256) void bn_stats(const float* __restrict__ h, float* __restrict__ sum,
                                                float* __restrict__ sq, int N){
  int c = threadIdx.x & 127;
  int sub = threadIdx.x >> 7;
  float s = 0.f, q = 0.f;
  for (int n = blockIdx.x*2 + sub; n < N; n += gridDim.x*2){
    float v = h[(size_t)n*128 + c];
    s += v; q += v*v;
  }
  __shared__ float ls[256], lq[256];
  ls[threadIdx.x] = s; lq[threadIdx.x] = q;
  __syncthreads();
  if (threadIdx.x < 128){
    s = ls[threadIdx.x] + ls[threadIdx.x + 128];
    q = lq[threadIdx.x] + lq[threadIdx.x + 128];
    atomicAdd(&sum[c], s);
    atomicAdd(&sq[c], q);
  }
}
__global__ void bn_final(const float* __restrict__ sum, const float* __restrict__ sq,
                         const float* __restrict__ gamma, const float* __restrict__ beta,
                         float* __restrict__ scale, float* __restrict__ shift, int N){
  int c = threadIdx.x;
  float mean = sum[c] / (float)N;
  float var  = sq[c] / (float)N - mean*mean;
  var = fmaxf(var, 0.f);
  float rstd = rsqrtf(var + 1e-5f);
  float sc = gamma[c] * rstd;
  scale[c] = sc;
  shift[c] = beta[c] - mean*sc;
}
// BN + ReLU + residual; dual write: fp32 residual stream + bf16 GEMM feed
__global__ __launch_bounds__(256) void bn_elem(float* __restrict__ hg, const float* __restrict__ hprev,
                                               const float* __restrict__ scale, const float* __restrict__ shift,
                                               unsigned short* __restrict__ hbf, int total4){
  int i = blockIdx.x*256 + threadIdx.x;
  if (i >= total4) return;
  int c = (i*4) & 127;
  float4 v  = ((const float4*)hg)[i];
  float4 pv = ((const float4*)hprev)[i];
  float4 sc = *(const float4*)(scale + c);
  float4 sh = *(const float4*)(shift + c);
  float r0 = v.x*sc.x + sh.x; r0 = r0 > 0.f ? r0 : 0.f; r0 += pv.x;
  float r1 = v.y*sc.y + sh.y; r1 = r1 > 0.f ? r1 : 0.f; r1 += pv.y;
  float r2 = v.z*sc.z + sh.z; r2 = r2 > 0.f ? r2 : 0.f; r2 += pv.z;
  float r3 = v.w*sc.w + sh.w; r3 = r3 > 0.f ? r3 : 0.f; r3 += pv.w;
  float4 o; o.x = r0; o.y = r1; o.z = r2; o.w = r3;
  ((float4*)hg)[i] = o;
  ushort4 ob; ob.x = f2bf(r0); ob.y = f2bf(r1); ob.z = f2bf(r2); ob.w = f2bf(r3);
  ((ushort4*)hbf)[i] = ob;
}

// ---------------- host ----------------
extern "C" void kernel_launch(void* const* d_in, const int* in_sizes, int n_in,
                              void* d_out, int out_size, void* d_ws, size_t ws_size,
                              hipStream_t stream)
{
  const void* x        = d_in[0];
  const int*  ei       = (const int*)d_in[1];
  const void* eattr    = d_in[2];
  int N = in_sizes[0] / 64;
  int E = in_sizes[1] / 2;

  char* p = (char*)d_ws;
  auto alloc = [&](size_t bytes)->char* {
    char* r = p; p += (bytes + 255) & ~(size_t)255; return r;
  };
  // zero-region first (one memset)
  int*   deg    = (int*)alloc((size_t)N*4);
  int*   cursor = (int*)alloc((size_t)N*4);
  float* bnsum  = (float*)alloc(3*128*4);
  float* bnsq   = (float*)alloc(3*128*4);
  size_t zbytes = (size_t)(p - (char*)deg);
  int*   dflag  = (int*)alloc(256);
  int*   row    = (int*)alloc(((size_t)N + 1)*4);
  int*   part   = (int*)alloc(1024*4);
  int*   csr_src= (int*)alloc((size_t)E*4);
  int*   csr_eid= (int*)alloc((size_t)E*4);
  int*   csr_dst= (int*)alloc((size_t)E*4);
  unsigned short* ecsr = (unsigned short*)alloc((size_t)E*16*2);
  float* hA     = (float*)alloc((size_t)N*128*4);
  float* hB     = (float*)alloc((size_t)N*128*4);
  unsigned short* hAb = (unsigned short*)alloc((size_t)N*128*2);
  unsigned short* hBb = (unsigned short*)alloc((size_t)N*128*2);
  unsigned short* xhb = (unsigned short*)alloc((size_t)N*128*2);
  float* a_src  = (float*)alloc((size_t)N*4*4);
  float* a_dst  = (float*)alloc((size_t)N*4*4);
  float* alphaS = (float*)alloc((size_t)N*4*4);
  float4* alphaA= (float4*)alloc((size_t)E*16);
  float* ea_mean= (float*)alloc((size_t)N*16*4);
  float* deg_ind= (float*)alloc((size_t)N*4);
  float* Mmat   = (float*)alloc(16*12*4);
  float* cbias  = (float*)alloc(12*4);
  float* bnscale= (float*)alloc(128*4);
  float* bnshift= (float*)alloc(128*4);
  unsigned short* xc  = (unsigned short*)alloc((size_t)N*64*2);
  float* wc     = (float*)alloc(130000*4);

  // canonical weight buffers (fp32)
  int   woff[14] = {0, 8192, 8320, 10368, 10496, 59648, 108800, 109184,
                    109568, 109952, 110336, 110720, 111104, 127488};
  int   wcnt[14] = {8192, 128, 2048, 128, 49152, 49152, 384, 384, 384, 384, 384, 384, 16384, 128};
  CvList L; L.n = 14;
  for (int a = 0; a < 14; ++a){ L.src[a] = d_in[3+a]; L.dst[a] = wc + woff[a]; L.cnt[a] = wcnt[a]; }
  float* cW_atom = wc + woff[0];  float* cb_atom = wc + woff[1];
  float* cW_bond = wc + woff[2];  float* cb_bond = wc + woff[3];
  float* cW_lin  = wc + woff[4];  float* cW_edge = wc + woff[5];
  float* catt_s  = wc + woff[6];  float* catt_d  = wc + woff[7];
  float* catt_e  = wc + woff[8];  float* cbconv  = wc + woff[9];
  float* cgamma  = wc + woff[10]; float* cbeta   = wc + woff[11];
  float* cW_out  = wc + woff[12]; float* cb_out  = wc + woff[13];

  hipMemsetAsync(deg, 0, zbytes, stream);
  detect_dtype<<<1, 256, 0, stream>>>((const unsigned short*)x, dflag);
  conv_weights<<<64, 256, 0, stream>>>(L, dflag);
  conv_bf16<<<(N*16 + 255)/256, 256, 0, stream>>>(x, xc, N*16, dflag);

  precompute_M<<<1, 256, 0, stream>>>(cW_edge, catt_e, cW_bond, cb_bond, Mmat, cbias);
  deg_count<<<(E + 255)/256, 256, 0, stream>>>(ei, E, deg);
  int P = (N + 1023)/1024;
  scan_part<<<P, 256, 0, stream>>>(deg, part, N);
  scan_top<<<1, 64, 0, stream>>>(part, P);
  scan_write<<<P, 256, 0, stream>>>(deg, part, row, N, E);
  csr_fill<<<(E + 255)/256, 256, 0, stream>>>(ei, E, row, cursor, csr_src, csr_eid, csr_dst);
  gather_eattr<<<(E + 255)/256, 256, 0, stream>>>(eattr, csr_eid, ecsr, E, dflag);
  ea_mean_k<<<(N*4 + 255)/256, 256, 0, stream>>>(ecsr, row, ea_mean, deg_ind, N);

  // atom embedding: hA(fp32) + hAb(bf16) = x @ W_atom + b_atom
  mfma_lin<64, 2, false><<<(N + 63)/64, 256, 0, stream>>>(xc, cW_atom, cb_atom, hA, hAb, N, dflag,
      nullptr, nullptr, nullptr, nullptr, nullptr, nullptr, nullptr, nullptr, nullptr);

  float* cur = hA; float* oth = hB;
  unsigned short* curb = hAb; unsigned short* othb = hBb;
  for (int l = 0; l < 3; ++l){
    mfma_lin<128, 0, true><<<(N + 63)/64, 256, 0, stream>>>(curb, cW_lin + (size_t)l*16384, nullptr,
        xhb, nullptr, N, dflag,
        catt_s + l*128, catt_d + l*128, Mmat + l*4, cbias + l*4,
        ea_mean, deg_ind, a_src, a_dst, alphaS);
    edge_alpha<<<(E + 255)/256, 256, 0, stream>>>(ecsr, csr_src, csr_dst, a_src, a_dst,
                                                  Mmat, cbias, alphaA, E, l);
    gat_agg<<<(N + 3)/4, 256, 0, stream>>>(xhb, alphaA, csr_src, row, (const float4*)alphaS,
                                           cbconv, oth, N, l);
    bn_stats<<<256, 256, 0, stream>>>(oth, bnsum + l*128, bnsq + l*128, N);
    bn_final<<<1, 128, 0, stream>>>(bnsum + l*128, bnsq + l*128, cgamma + l*128, cbeta + l*128,
                                    bnscale, bnshift, N);
    bn_elem<<<((N*128/4) + 255)/256, 256, 0, stream>>>(oth, cur, bnscale, bnshift, othb, N*128/4);
    float* t = cur; cur = oth; oth = t;
    unsigned short* tb = curb; curb = othb; othb = tb;
  }
  // final projection, output dtype per detected storage
  mfma_lin<128, 1, false><<<(N + 63)/64, 256, 0, stream>>>(curb, cW_out, cb_out, d_out, nullptr, N, dflag,
      nullptr, nullptr, nullptr, nullptr, nullptr, nullptr, nullptr, nullptr, nullptr);
}